// Round 4
// baseline (428.316 us; speedup 1.0000x reference)
//
#include <hip/hip_runtime.h>
#include <hip/hip_bf16.h>

// FFB encoder, MI355X. Round 4: barrier-free, LDS-free, register-resident.
// Each wave owns 32 points for the whole chain. MFMA: A = W (m=h_out),
// B = X (n=point). C/D layout (point in lane, h in regs) == next layer's
// B-operand layout up to a half-wave swap of values with (h mod 16) in 4..11,
// done with ds_bpermute (lane^32). W pre-rearranged into fragment-linear
// order by prep kernel -> perfectly coalesced b128 streams from L2.
// Mid = 3-mult split-bf16, high = 1-mult bf16-hi, hw v_sin (fract for grid).

typedef __bf16 bf16_t;
typedef __attribute__((ext_vector_type(8))) __bf16 bf16x8;
typedef __attribute__((ext_vector_type(4))) float f32x4;
typedef __attribute__((ext_vector_type(16))) float f32x16;

#define C56R 8.9126768f               // 56 / (2*pi)
#define INV7 0.14285714285714285f

// ws layout (bytes)
#define OFF_WMF   0        // mid W hi, frag-ordered [7][4mt][8kc][64lane][8bf16]
#define OFF_WMFLO 229376   // mid W lo, same order
#define OFF_WHF   458752   // high W hi, same order
#define OFF_EPM   688128   // [7][2hf][4mt][16r] float4 {ap0, ap1, C56R*bm, C56R*bh}
// total 702464

union ChunkU { bf16x8 v; unsigned int d[4]; };

__device__ __forceinline__ unsigned short bfbits(float x) {
  bf16_t b = (bf16_t)x;
  return __builtin_bit_cast(unsigned short, b);
}
__device__ __forceinline__ float bf2f(unsigned short u) {
  return __builtin_bit_cast(float, (unsigned int)u << 16);
}
// v0,v1 -> packed bf16-hi pair and bf16-lo (residual) pair
__device__ __forceinline__ void pack2(float v0, float v1,
                                      unsigned int& ph, unsigned int& pl) {
  unsigned short h0 = bfbits(v0), h1 = bfbits(v1);
  ph = (unsigned int)h0 | ((unsigned int)h1 << 16);
  float l0 = v0 - bf2f(h0), l1 = v1 - bf2f(h1);
  pl = (unsigned int)bfbits(l0) | ((unsigned int)bfbits(l1) << 16);
}
// 16 C-layout values (as 8 packed pairs P) -> two B-layout chunks via
// half-wave exchange. P[0..7] = pairs (r0r1)(r2r3)(r4r5)(r6r7)(r8r9)(r10r11)(r12r13)(r14r15).
__device__ __forceinline__ void exch(const unsigned int P[8], int hf, int bpidx,
                                     ChunkU& cA, ChunkU& cB) {
  unsigned int t0 = hf ? P[0] : P[2];
  unsigned int t1 = hf ? P[1] : P[3];
  unsigned int t2 = hf ? P[4] : P[6];
  unsigned int t3 = hf ? P[5] : P[7];
  unsigned int r0 = (unsigned int)__builtin_amdgcn_ds_bpermute(bpidx, (int)t0);
  unsigned int r1 = (unsigned int)__builtin_amdgcn_ds_bpermute(bpidx, (int)t1);
  unsigned int r2 = (unsigned int)__builtin_amdgcn_ds_bpermute(bpidx, (int)t2);
  unsigned int r3 = (unsigned int)__builtin_amdgcn_ds_bpermute(bpidx, (int)t3);
  cA.d[0] = hf ? r0 : P[0];
  cA.d[1] = hf ? r1 : P[1];
  cA.d[2] = hf ? P[2] : r0;
  cA.d[3] = hf ? P[3] : r1;
  cB.d[0] = hf ? r2 : P[4];
  cB.d[1] = hf ? r3 : P[5];
  cB.d[2] = hf ? P[6] : r2;
  cB.d[3] = hf ? P[7] : r3;
}

__global__ void ffb_prep(const float* __restrict__ ffnA, const float* __restrict__ sigma,
                         const float* __restrict__ Wm, const float* __restrict__ bm,
                         const float* __restrict__ Wh, const float* __restrict__ bh,
                         unsigned char* __restrict__ ws) {
  int i = blockIdx.x * 256 + threadIdx.x;  // 448*256 = 114688 exactly
  bf16_t* wmf = (bf16_t*)(ws + OFF_WMF);
  bf16_t* wml = (bf16_t*)(ws + OFF_WMFLO);
  bf16_t* whf = (bf16_t*)(ws + OFF_WHF);
  {
    // fragment reorder: [it][mt][kc][lane][j]
    int j    = i & 7;
    int lane = (i >> 3) & 63;
    int kc   = (i >> 9) & 7;
    int mt   = (i >> 12) & 3;
    int it   = i >> 14;                       // 0..6
    int ho   = (mt << 5) + (lane & 31);
    int hin  = (kc << 4) + ((lane >> 5) << 3) + j;
    int src  = (it << 14) + (ho << 7) + hin;
    float w  = Wm[src];
    bf16_t h = (bf16_t)w;
    wmf[i] = h;
    wml[i] = (bf16_t)(w - (float)h);
    whf[i] = (bf16_t)Wh[src];
  }
  if (i < 896) {
    int r  = i & 15;
    int mt = (i >> 4) & 3;
    int hf = (i >> 6) & 1;
    int it = i >> 7;                          // 0..6
    int h  = (mt << 5) + (r & 3) + ((r >> 2) << 3) + (hf << 2);
    float sg = sigma[it];
    f32x4 e;
    e.x = ffnA[it * 256 + h] * sg;
    e.y = ffnA[it * 256 + 128 + h] * sg;
    e.z = C56R * bm[it * 128 + h];
    e.w = C56R * bh[it * 128 + h];
    ((f32x4*)(ws + OFF_EPM))[i] = e;
  }
}

__launch_bounds__(64, 2)
__global__ void ffb_main(const float* __restrict__ pos,
                         const float* __restrict__ gfeat,
                         const float* __restrict__ W0,
                         const float* __restrict__ b0,
                         const unsigned char* __restrict__ ws,
                         float* __restrict__ out) {
  const int L  = threadIdx.x;       // 0..63
  const int p  = L & 31;            // point within wave (n-dim & lane)
  const int hf = L >> 5;            // half selector
  const int bpidx  = ((L ^ 32) << 2);
  const int n      = (blockIdx.x << 5) + p;

  const bf16_t* __restrict__ WMF = (const bf16_t*)(ws + OFF_WMF);
  const bf16_t* __restrict__ WML = (const bf16_t*)(ws + OFF_WMFLO);
  const bf16_t* __restrict__ WHF = (const bf16_t*)(ws + OFF_WHF);
  const f32x4*  __restrict__ EPM = (const f32x4*)(ws + OFF_EPM);
  const float*  __restrict__ EPW = (const float*)(ws + OFF_EPM);

  const float p0 = pos[n * 3 + 0], p1 = pos[n * 3 + 1], p2 = pos[n * 3 + 2];
  if (hf == 0) {
    out[n * 131 + 0] = (p0 + 1.f) * 0.5f;
    out[n * 131 + 1] = (p1 + 1.f) * 0.5f;
    out[n * 131 + 2] = (p2 + 1.f) * 0.5f;
  }

  // ---- layer 0: x0 in B-layout chunks. lane holds h = 16q + 8hf + j.
  ChunkU xh[8], xl[8];
  #pragma unroll
  for (int q = 0; q < 8; ++q) {
    #pragma unroll
    for (int jp = 0; jp < 4; ++jp) {
      int h0 = (q << 4) + (hf << 3) + 2 * jp;
      float d0 = __builtin_fmaf(p2, W0[h0*3+2], __builtin_fmaf(p1, W0[h0*3+1], p0 * W0[h0*3+0]));
      float d1 = __builtin_fmaf(p2, W0[h0*3+5], __builtin_fmaf(p1, W0[h0*3+4], p0 * W0[h0*3+3]));
      float v0 = __builtin_amdgcn_sinf(C56R * (d0 + b0[h0]));
      float v1 = __builtin_amdgcn_sinf(C56R * (d1 + b0[h0 + 1]));
      pack2(v0, v1, xh[q].d[jp], xl[q].d[jp]);
    }
  }

  f32x16 buf[4];
  #pragma unroll
  for (int mt = 0; mt < 4; ++mt)
    #pragma unroll
    for (int r = 0; r < 16; ++r) buf[mt][r] = 0.f;

  for (int it = 0; it < 8; ++it) {
    // ---- high pass: weights it-1 applied to current X ----
    if (it > 0) {
      f32x16 acc[4];
      #pragma unroll
      for (int mt = 0; mt < 4; ++mt)
        #pragma unroll
        for (int r = 0; r < 16; ++r) acc[mt][r] = 0.f;
      const bf16_t* wb = WHF + ((it - 1) << 14) + (L << 3);
      #pragma unroll
      for (int kc = 0; kc < 8; ++kc) {
        #pragma unroll
        for (int mt = 0; mt < 4; ++mt) {
          bf16x8 f = *(const bf16x8*)(wb + (((mt << 3) + kc) << 9));
          acc[mt] = __builtin_amdgcn_mfma_f32_32x32x16_bf16(f, xh[kc].v, acc[mt], 0, 0, 0);
        }
      }
      const int ebase = ((((it - 1) << 1) + hf) << 2);
      #pragma unroll
      for (int mt = 0; mt < 4; ++mt) {
        #pragma unroll
        for (int r = 0; r < 16; ++r) {
          float cbh = EPW[((ebase + mt) * 16 + r) * 4 + 3];
          buf[mt][r] += __builtin_amdgcn_sinf(__builtin_fmaf(acc[mt][r], C56R, cbh));
        }
      }
    }

    // ---- mid pass: weights it, X -> X_next (in-place per tile) ----
    if (it < 7) {
      f32x16 acc[4];
      #pragma unroll
      for (int mt = 0; mt < 4; ++mt)
        #pragma unroll
        for (int r = 0; r < 16; ++r) acc[mt][r] = 0.f;
      const bf16_t* wh = WMF + (it << 14) + (L << 3);
      const bf16_t* wl = WML + (it << 14) + (L << 3);
      #pragma unroll
      for (int kc = 0; kc < 8; ++kc) {
        #pragma unroll
        for (int mt = 0; mt < 4; ++mt) {
          const int off = (((mt << 3) + kc) << 9);
          bf16x8 fh = *(const bf16x8*)(wh + off);
          bf16x8 fl = *(const bf16x8*)(wl + off);
          acc[mt] = __builtin_amdgcn_mfma_f32_32x32x16_bf16(fh, xh[kc].v, acc[mt], 0, 0, 0);
          acc[mt] = __builtin_amdgcn_mfma_f32_32x32x16_bf16(fl, xh[kc].v, acc[mt], 0, 0, 0);
          acc[mt] = __builtin_amdgcn_mfma_f32_32x32x16_bf16(fh, xl[kc].v, acc[mt], 0, 0, 0);
        }
      }
      const float g0 = gfeat[n * 17 + 3 + 2 * it];
      const float g1 = gfeat[n * 17 + 4 + 2 * it];
      const int ebase = (((it << 1) + hf) << 2);
      #pragma unroll
      for (int mt = 0; mt < 4; ++mt) {
        unsigned int Ph[8], Pl[8];
        #pragma unroll
        for (int rp = 0; rp < 8; ++rp) {
          f32x4 e0 = EPM[(ebase + mt) * 16 + 2 * rp];
          f32x4 e1 = EPM[(ebase + mt) * 16 + 2 * rp + 1];
          float sg0 = __builtin_amdgcn_sinf(__builtin_amdgcn_fractf(__builtin_fmaf(g1, e0.y, g0 * e0.x)));
          float sg1 = __builtin_amdgcn_sinf(__builtin_amdgcn_fractf(__builtin_fmaf(g1, e1.y, g0 * e1.x)));
          float sm0 = __builtin_amdgcn_sinf(__builtin_fmaf(acc[mt][2*rp],   C56R, e0.z));
          float sm1 = __builtin_amdgcn_sinf(__builtin_fmaf(acc[mt][2*rp+1], C56R, e1.z));
          pack2(sg0 + sm0, sg1 + sm1, Ph[rp], Pl[rp]);
        }
        exch(Ph, hf, bpidx, xh[2*mt], xh[2*mt + 1]);
        exch(Pl, hf, bpidx, xl[2*mt], xl[2*mt + 1]);
      }
    }
  }

  // ---- final store: buf/7, each (point,h) lives in exactly one lane.
  float* op = out + n * 131 + 3;
  #pragma unroll
  for (int mt = 0; mt < 4; ++mt) {
    #pragma unroll
    for (int r = 0; r < 16; ++r) {
      const int h = (mt << 5) + (r & 3) + ((r >> 2) << 3) + (hf << 2);
      op[h] = buf[mt][r] * INV7;
    }
  }
}

extern "C" void kernel_launch(void* const* d_in, const int* in_sizes, int n_in,
                              void* d_out, int out_size, void* d_ws, size_t ws_size,
                              hipStream_t stream) {
  (void)in_sizes; (void)n_in; (void)out_size; (void)ws_size;
  const float* pos   = (const float*)d_in[0];
  const float* gfeat = (const float*)d_in[1];
  const float* ffnA  = (const float*)d_in[2];
  const float* sigma = (const float*)d_in[3];
  const float* W0    = (const float*)d_in[4];
  const float* b0    = (const float*)d_in[5];
  const float* Wm    = (const float*)d_in[6];
  const float* bm    = (const float*)d_in[7];
  const float* Wh    = (const float*)d_in[8];
  const float* bh    = (const float*)d_in[9];
  float* out = (float*)d_out;
  unsigned char* ws = (unsigned char*)d_ws;

  hipLaunchKernelGGL(ffb_prep, dim3(448), dim3(256), 0, stream,
                     ffnA, sigma, Wm, bm, Wh, bh, ws);
  hipLaunchKernelGGL(ffb_main, dim3(4096), dim3(64), 0, stream,
                     pos, gfeat, W0, b0, ws, out);
}

// Round 5
// 301.220 us; speedup vs baseline: 1.4219x; 1.4219x over previous
//
#include <hip/hip_runtime.h>
#include <hip/hip_bf16.h>

// FFB encoder, MI355X. Round 5: X register-resident per wave (r4 structure,
// verified numerics/exchange), W staged per-level into LDS by the whole WG
// (8x reuse, 2 barriers/level). WG = 512 thr = 8 waves x 32 points.
// ws layout per level L in 0..6: WMHI @ L*98304, WMLO @ +32768, WHI @ +65536.
// Level-it stage source = ws + it*98304 - 32768 (one linear 96 KB block:
// [WHI(it-1) | WMHI(it) | WMLO(it)]), clamped at the edges (it=0 high and
// it=7 mid sections are garbage and unused).

typedef __bf16 bf16_t;
typedef __attribute__((ext_vector_type(8))) __bf16 bf16x8;
typedef __attribute__((ext_vector_type(4))) float f32x4;
typedef __attribute__((ext_vector_type(16))) float f32x16;

#define C56R 8.9126768f               // 56 / (2*pi)
#define INV7 0.14285714285714285f

#define OFF_EPM  688128    // [7][2hf][4mt][16r] float4 {ap0, ap1, C56R*bm, C56R*bh}
#define WS_TOTAL 702464

union ChunkU { bf16x8 v; unsigned int d[4]; };

__device__ __forceinline__ unsigned short bfbits(float x) {
  bf16_t b = (bf16_t)x;
  return __builtin_bit_cast(unsigned short, b);
}
__device__ __forceinline__ float bf2f(unsigned short u) {
  return __builtin_bit_cast(float, (unsigned int)u << 16);
}
__device__ __forceinline__ void pack2(float v0, float v1,
                                      unsigned int& ph, unsigned int& pl) {
  unsigned short h0 = bfbits(v0), h1 = bfbits(v1);
  ph = (unsigned int)h0 | ((unsigned int)h1 << 16);
  float l0 = v0 - bf2f(h0), l1 = v1 - bf2f(h1);
  pl = (unsigned int)bfbits(l0) | ((unsigned int)bfbits(l1) << 16);
}
// 16 C-layout values (8 packed pairs) -> two B-layout chunks via half-wave
// exchange (values with (h mod 16) in 4..11 swap lane-halves).
__device__ __forceinline__ void exch(const unsigned int P[8], int hf, int bpidx,
                                     ChunkU& cA, ChunkU& cB) {
  unsigned int t0 = hf ? P[0] : P[2];
  unsigned int t1 = hf ? P[1] : P[3];
  unsigned int t2 = hf ? P[4] : P[6];
  unsigned int t3 = hf ? P[5] : P[7];
  unsigned int r0 = (unsigned int)__builtin_amdgcn_ds_bpermute(bpidx, (int)t0);
  unsigned int r1 = (unsigned int)__builtin_amdgcn_ds_bpermute(bpidx, (int)t1);
  unsigned int r2 = (unsigned int)__builtin_amdgcn_ds_bpermute(bpidx, (int)t2);
  unsigned int r3 = (unsigned int)__builtin_amdgcn_ds_bpermute(bpidx, (int)t3);
  cA.d[0] = hf ? r0 : P[0];
  cA.d[1] = hf ? r1 : P[1];
  cA.d[2] = hf ? P[2] : r0;
  cA.d[3] = hf ? P[3] : r1;
  cB.d[0] = hf ? r2 : P[4];
  cB.d[1] = hf ? r3 : P[5];
  cB.d[2] = hf ? P[6] : r2;
  cB.d[3] = hf ? P[7] : r3;
}

__global__ void ffb_prep(const float* __restrict__ ffnA, const float* __restrict__ sigma,
                         const float* __restrict__ Wm, const float* __restrict__ bm,
                         const float* __restrict__ Wh, const float* __restrict__ bh,
                         unsigned char* __restrict__ ws) {
  int i = blockIdx.x * 256 + threadIdx.x;  // 448*256 = 114688 exactly
  {
    int fidx = i & 16383;                  // frag index within a 16384-elem level
    int Lv   = i >> 14;                    // level 0..6
    int j    = fidx & 7;
    int lane = (fidx >> 3) & 63;
    int kc   = (fidx >> 9) & 7;
    int mt   = (fidx >> 12) & 3;
    int ho   = (mt << 5) + (lane & 31);
    int hin  = (kc << 4) + ((lane >> 5) << 3) + j;
    int src  = (Lv << 14) + (ho << 7) + hin;
    float w  = Wm[src];
    bf16_t h = (bf16_t)w;
    *(bf16_t*)(ws + (size_t)Lv * 98304 + fidx * 2)         = h;
    *(bf16_t*)(ws + (size_t)Lv * 98304 + 32768 + fidx * 2) = (bf16_t)(w - (float)h);
    *(bf16_t*)(ws + (size_t)Lv * 98304 + 65536 + fidx * 2) = (bf16_t)Wh[src];
  }
  if (i < 896) {
    int r  = i & 15;
    int mt = (i >> 4) & 3;
    int hf = (i >> 6) & 1;
    int it = i >> 7;                          // 0..6
    int h  = (mt << 5) + (r & 3) + ((r >> 2) << 3) + (hf << 2);
    float sg = sigma[it];
    f32x4 e;
    e.x = ffnA[it * 256 + h] * sg;
    e.y = ffnA[it * 256 + 128 + h] * sg;
    e.z = C56R * bm[it * 128 + h];
    e.w = C56R * bh[it * 128 + h];
    ((f32x4*)(ws + OFF_EPM))[i] = e;
  }
}

__launch_bounds__(512, 2)
__global__ void ffb_main(const float* __restrict__ pos,
                         const float* __restrict__ gfeat,
                         const float* __restrict__ W0,
                         const float* __restrict__ b0,
                         const unsigned char* __restrict__ ws,
                         float* __restrict__ out) {
  __shared__ __align__(16) unsigned char sW[98304];  // [high 32K | midhi 32K | midlo 32K]

  const int tid  = threadIdx.x;
  const int L    = tid & 63;
  const int wave = tid >> 6;        // 0..7
  const int p    = L & 31;
  const int hf   = L >> 5;
  const int bpidx = (L ^ 32) << 2;
  const int n    = (blockIdx.x << 8) + (wave << 5) + p;

  const f32x4* __restrict__ EPM = (const f32x4*)(ws + OFF_EPM);
  const float* __restrict__ EPW = (const float*)(ws + OFF_EPM);

  const float p0 = pos[n * 3 + 0], p1 = pos[n * 3 + 1], p2 = pos[n * 3 + 2];
  if (hf == 0) {
    out[n * 131 + 0] = (p0 + 1.f) * 0.5f;
    out[n * 131 + 1] = (p1 + 1.f) * 0.5f;
    out[n * 131 + 2] = (p2 + 1.f) * 0.5f;
  }

  // ---- layer 0: x0 in B-layout chunks. lane holds h = 16q + 8hf + j.
  ChunkU xh[8], xl[8];
  #pragma unroll
  for (int q = 0; q < 8; ++q) {
    #pragma unroll
    for (int jp = 0; jp < 4; ++jp) {
      int h0 = (q << 4) + (hf << 3) + 2 * jp;
      float d0 = __builtin_fmaf(p2, W0[h0*3+2], __builtin_fmaf(p1, W0[h0*3+1], p0 * W0[h0*3+0]));
      float d1 = __builtin_fmaf(p2, W0[h0*3+5], __builtin_fmaf(p1, W0[h0*3+4], p0 * W0[h0*3+3]));
      float v0 = __builtin_amdgcn_sinf(C56R * (d0 + b0[h0]));
      float v1 = __builtin_amdgcn_sinf(C56R * (d1 + b0[h0 + 1]));
      pack2(v0, v1, xh[q].d[jp], xl[q].d[jp]);
    }
  }

  f32x16 buf[4];
  #pragma unroll
  for (int mt = 0; mt < 4; ++mt)
    #pragma unroll
    for (int r = 0; r < 16; ++r) buf[mt][r] = 0.f;

  for (int it = 0; it < 8; ++it) {
    // ---- stage W block for this level: [WHI(it-1) | WMHI(it) | WMLO(it)]
    __syncthreads();   // previous level's consumers done with sW
    {
      const int wsbase = it * 98304 - 32768;
      #pragma unroll
      for (int c = 0; c < 12; ++c) {
        int off = wsbase + (c << 13) + (tid << 4);
        if ((unsigned)off >= (unsigned)(WS_TOTAL - 16)) off = 0;  // it=0/it=7 edges
        *(f32x4*)(&sW[(c << 13) + (tid << 4)]) = *(const f32x4*)(ws + off);
      }
    }
    __syncthreads();

    // ---- high pass: weights it-1 applied to current X ----
    if (it > 0) {
      f32x16 acc[4];
      #pragma unroll
      for (int mt = 0; mt < 4; ++mt)
        #pragma unroll
        for (int r = 0; r < 16; ++r) acc[mt][r] = 0.f;
      #pragma unroll
      for (int kc = 0; kc < 8; ++kc) {
        #pragma unroll
        for (int mt = 0; mt < 4; ++mt) {
          bf16x8 f = *(const bf16x8*)(&sW[(((mt << 3) + kc) << 10) + (L << 4)]);
          acc[mt] = __builtin_amdgcn_mfma_f32_32x32x16_bf16(f, xh[kc].v, acc[mt], 0, 0, 0);
        }
      }
      const int ebase = ((((it - 1) << 1) + hf) << 2);
      #pragma unroll
      for (int mt = 0; mt < 4; ++mt) {
        #pragma unroll
        for (int r = 0; r < 16; ++r) {
          float cbh = EPW[((ebase + mt) * 16 + r) * 4 + 3];
          buf[mt][r] += __builtin_amdgcn_sinf(__builtin_fmaf(acc[mt][r], C56R, cbh));
        }
      }
    }

    // ---- mid pass: weights it, X -> X_next ----
    if (it < 7) {
      f32x16 acc[4];
      #pragma unroll
      for (int mt = 0; mt < 4; ++mt)
        #pragma unroll
        for (int r = 0; r < 16; ++r) acc[mt][r] = 0.f;
      #pragma unroll
      for (int kc = 0; kc < 8; ++kc) {
        #pragma unroll
        for (int mt = 0; mt < 4; ++mt) {
          const int off = (((mt << 3) + kc) << 10) + (L << 4);
          bf16x8 fh = *(const bf16x8*)(&sW[32768 + off]);
          bf16x8 fl = *(const bf16x8*)(&sW[65536 + off]);
          acc[mt] = __builtin_amdgcn_mfma_f32_32x32x16_bf16(fh, xh[kc].v, acc[mt], 0, 0, 0);
          acc[mt] = __builtin_amdgcn_mfma_f32_32x32x16_bf16(fl, xh[kc].v, acc[mt], 0, 0, 0);
          acc[mt] = __builtin_amdgcn_mfma_f32_32x32x16_bf16(fh, xl[kc].v, acc[mt], 0, 0, 0);
        }
      }
      const float g0 = gfeat[n * 17 + 3 + 2 * it];
      const float g1 = gfeat[n * 17 + 4 + 2 * it];
      const int ebase = (((it << 1) + hf) << 2);
      #pragma unroll
      for (int mt = 0; mt < 4; ++mt) {
        unsigned int Ph[8], Pl[8];
        #pragma unroll
        for (int rp = 0; rp < 8; ++rp) {
          f32x4 e0 = EPM[(ebase + mt) * 16 + 2 * rp];
          f32x4 e1 = EPM[(ebase + mt) * 16 + 2 * rp + 1];
          float sg0 = __builtin_amdgcn_sinf(__builtin_amdgcn_fractf(__builtin_fmaf(g1, e0.y, g0 * e0.x)));
          float sg1 = __builtin_amdgcn_sinf(__builtin_amdgcn_fractf(__builtin_fmaf(g1, e1.y, g0 * e1.x)));
          float sm0 = __builtin_amdgcn_sinf(__builtin_fmaf(acc[mt][2*rp],   C56R, e0.z));
          float sm1 = __builtin_amdgcn_sinf(__builtin_fmaf(acc[mt][2*rp+1], C56R, e1.z));
          pack2(sg0 + sm0, sg1 + sm1, Ph[rp], Pl[rp]);
        }
        exch(Ph, hf, bpidx, xh[2*mt], xh[2*mt + 1]);
        exch(Pl, hf, bpidx, xl[2*mt], xl[2*mt + 1]);
      }
    }
  }

  // ---- final store: buf/7 — each (point,h) lives in exactly one lane.
  float* op = out + (size_t)n * 131 + 3;
  #pragma unroll
  for (int mt = 0; mt < 4; ++mt) {
    #pragma unroll
    for (int r = 0; r < 16; ++r) {
      const int h = (mt << 5) + (r & 3) + ((r >> 2) << 3) + (hf << 2);
      op[h] = buf[mt][r] * INV7;
    }
  }
}

extern "C" void kernel_launch(void* const* d_in, const int* in_sizes, int n_in,
                              void* d_out, int out_size, void* d_ws, size_t ws_size,
                              hipStream_t stream) {
  (void)in_sizes; (void)n_in; (void)out_size; (void)ws_size;
  const float* pos   = (const float*)d_in[0];
  const float* gfeat = (const float*)d_in[1];
  const float* ffnA  = (const float*)d_in[2];
  const float* sigma = (const float*)d_in[3];
  const float* W0    = (const float*)d_in[4];
  const float* b0    = (const float*)d_in[5];
  const float* Wm    = (const float*)d_in[6];
  const float* bm    = (const float*)d_in[7];
  const float* Wh    = (const float*)d_in[8];
  const float* bh    = (const float*)d_in[9];
  float* out = (float*)d_out;
  unsigned char* ws = (unsigned char*)d_ws;

  hipLaunchKernelGGL(ffb_prep, dim3(448), dim3(256), 0, stream,
                     ffnA, sigma, Wm, bm, Wh, bh, ws);
  hipLaunchKernelGGL(ffb_main, dim3(512), dim3(512), 0, stream,
                     pos, gfeat, W0, b0, ws, out);
}